// Round 2
// baseline (758.101 us; speedup 1.0000x reference)
//
#include <hip/hip_runtime.h>

// B=16384, S=32, E=128, H=4, DH=32, O=128. fp32 in/out.
// Split-fp32 (bf16 hi+lo, multi-product MFMA) for fp32-accurate scores.
// R2 change: weights pre-arranged in MFMA-fragment-major order in ws; main
// kernel loads W fragments straight from global (L1/L2-resident, coalesced
// dwordx4) -- no weight LDS staging, barriers drop ~44 -> ~11, LDS 46->23 KB.
//
// ws layout (unsigned short), 262144 B:
//   image(t,h) at (t*4+h)*8192 shorts: hi[4096] then lo[4096]
//   t<3 (wq,wk,wv): hi[r], r = kk*1024 + half*512 + lane*8 + j
//       element = W^T[d=half*16+(lane&15)][e=kk*32+(lane>>4)*8+j]
//   t=3 (wo):       hi[r], r = t8*512 + lane*8 + j
//       element = Wo^T[o=t8*16+(lane&15)][d=(lane>>4)*8+j]
//   scale 1/sqrt(32) folded into wq.

typedef __bf16 bf16x8 __attribute__((ext_vector_type(8)));
typedef float f32x4 __attribute__((ext_vector_type(4)));

union FragU { unsigned int w[4]; bf16x8 v; };

__device__ inline unsigned short f2bf(float f) {
  unsigned int u = __builtin_bit_cast(unsigned int, f);
  u += 0x7FFFu + ((u >> 16) & 1u);   // RTN-even
  return (unsigned short)(u >> 16);
}
__device__ inline float bf2f(unsigned short h) {
  return __builtin_bit_cast(float, (unsigned int)h << 16);
}

__device__ inline bf16x8 ld_frag8(const unsigned short* p) {
  // 8 consecutive bf16 in LDS, 8B-aligned -> two ds_read_b64
  FragU f;
  const uint2* q = (const uint2*)p;
  uint2 a = q[0], b = q[1];
  f.w[0] = a.x; f.w[1] = a.y; f.w[2] = b.x; f.w[3] = b.y;
  return f.v;
}

__device__ inline bf16x8 ld_gfrag(const unsigned short* p) {
  // 8 consecutive bf16 in global, 16B-aligned -> global_load_dwordx4
  FragU f;
  uint4 v = *(const uint4*)p;
  f.w[0] = v.x; f.w[1] = v.y; f.w[2] = v.z; f.w[3] = v.w;
  return f.v;
}

__device__ inline f32x4 mfma16(bf16x8 a, bf16x8 b, f32x4 c) {
  return __builtin_amdgcn_mfma_f32_16x16x32_bf16(a, b, c, 0, 0, 0);
}

// ---------- weight prep: fp32 -> fragment-major bf16 hi/lo images ----------
__global__ void prep_w(const float* __restrict__ wq, const float* __restrict__ wk,
                       const float* __restrict__ wv, const float* __restrict__ wo,
                       unsigned short* __restrict__ wsb) {
  int idx = blockIdx.x * 256 + threadIdx.x;     // 0..65535
  int t = idx >> 14;
  int h = (idx >> 12) & 3;
  int r = idx & 4095;
  const float* src = (t == 0) ? wq : (t == 1) ? wk : (t == 2) ? wv : wo;
  int L = (r >> 3) & 63, j = r & 7;
  float v;
  if (t < 3) {
    int kk = r >> 10, half = (r >> 9) & 1;
    int d = half * 16 + (L & 15);
    int e = kk * 32 + ((L >> 4) << 3) + j;
    v = src[h * 4096 + e * 32 + d];             // W[h][e][d]
    if (t == 0) v *= 0.17677669529663687f;      // 1/sqrt(32)
  } else {
    int t8 = r >> 9;
    int o = t8 * 16 + (L & 15);
    int d = ((L >> 4) << 3) + j;
    v = src[h * 4096 + d * 128 + o];            // Wo[h][d][o]
  }
  unsigned short hi = f2bf(v);
  unsigned short lo = f2bf(v - bf2f(hi));
  int base = (t * 4 + h) * 8192 + r;
  wsb[base] = hi;
  wsb[base + 4096] = lo;
}

// ---------------- main fused attention ----------------
// LDS (shorts), [36]-padded rows (72B stride -> <=2-way bank alias, free):
//   Kh  @0     [2 batch][32 t][36]   (hi)
//   Kl  @2304  [2][32][36]           (lo)
//   Vth @4608  [2][32 d][36 t]       (hi only; lo dropped, A is bf16 anyway)
//   Qh  @6912  [4 wave][16][36]      (Q-hi -> A -> Hd-hi, all same-wave)
//   Ql  @9216  [4 wave][16][36]      (Q-lo -> Hd-lo)
// total 11520 shorts = 23040 B. x-staging tile [32][132] hi@0 lo@4224 aliases.
#define LDS_TOT 11520

__global__ __launch_bounds__(256, 5) void attn_fused(
    const float* __restrict__ x, const unsigned short* __restrict__ wsb,
    float* __restrict__ out) {
  __shared__ unsigned short lds[LDS_TOT];
  const int tid = threadIdx.x;
  const int lane = tid & 63;
  const int wid = tid >> 6;       // 4 waves
  const int bl = wid >> 1;        // local batch 0/1
  const int hw = wid & 1;         // 16-row half
  const int sbase = hw << 4;
  const int col = lane & 15;
  const int quad = lane >> 4;
  const int lo8 = lane << 3;      // lane*8 shorts into frag images

  // ---- stage x -> hi/lo A-fragments in registers (rows sbase..sbase+15) ----
  bf16x8 xh[4], xl[4];
  for (int b = 0; b < 2; ++b) {
    const float4* xg = (const float4*)(x + ((long)(blockIdx.x * 2 + b) << 12));
#pragma unroll
    for (int it = 0; it < 4; ++it) {
      int f4 = it * 256 + tid;            // 1024 float4 per batch
      float4 v = xg[f4];
      int s = f4 >> 5;
      int e = (f4 & 31) << 2;
      unsigned short a0 = f2bf(v.x), b0 = f2bf(v.x - bf2f(a0));
      unsigned short a1 = f2bf(v.y), b1 = f2bf(v.y - bf2f(a1));
      unsigned short a2 = f2bf(v.z), b2 = f2bf(v.z - bf2f(a2));
      unsigned short a3 = f2bf(v.w), b3 = f2bf(v.w - bf2f(a3));
      uint2 ph, pl;
      ph.x = (unsigned)a0 | ((unsigned)a1 << 16);
      ph.y = (unsigned)a2 | ((unsigned)a3 << 16);
      pl.x = (unsigned)b0 | ((unsigned)b1 << 16);
      pl.y = (unsigned)b2 | ((unsigned)b3 << 16);
      *(uint2*)(lds + s * 132 + e) = ph;          // hi tile [32][132] @0
      *(uint2*)(lds + 4224 + s * 132 + e) = pl;   // lo tile @4224
    }
    __syncthreads();
    if (bl == b) {
#pragma unroll
      for (int kk = 0; kk < 4; ++kk) {
        xh[kk] = ld_frag8(lds + (sbase + col) * 132 + (kk << 5) + (quad << 3));
        xl[kk] = ld_frag8(lds + 4224 + (sbase + col) * 132 + (kk << 5) + (quad << 3));
      }
    }
    __syncthreads();
  }

  const long batch = (long)blockIdx.x * 2 + bl;
  const f32x4 zero = {0.f, 0.f, 0.f, 0.f};
  f32x4 oacc[8];
#pragma unroll
  for (int i = 0; i < 8; ++i) oacc[i] = zero;

  unsigned short* Kh = lds + 0 + bl * 1152;
  unsigned short* Kl = lds + 2304 + bl * 1152;
  unsigned short* Vth = lds + 4608 + bl * 1152;
  unsigned short* Qh = lds + 6912 + wid * 576;
  unsigned short* Ql = lds + 9216 + wid * 576;

  for (int hh = 0; hh < 4; ++hh) {
    if (hh) __syncthreads();   // sibling done reading prev K/V
    const unsigned short* wqb = wsb + (0 * 4 + hh) * 8192;
    const unsigned short* wkb = wsb + (1 * 4 + hh) * 8192;
    const unsigned short* wvb = wsb + (2 * 4 + hh) * 8192;
    const unsigned short* wob = wsb + (3 * 4 + hh) * 8192;

    // ======== Q = x*WqT, 3-product split (fp32-accurate) ========
    f32x4 c0 = zero, c1 = zero;
#pragma unroll
    for (int kk = 0; kk < 4; ++kk) {
      bf16x8 f0 = ld_gfrag(wqb + kk * 1024 + lo8);
      bf16x8 f1 = ld_gfrag(wqb + kk * 1024 + 512 + lo8);
      bf16x8 g0 = ld_gfrag(wqb + 4096 + kk * 1024 + lo8);
      bf16x8 g1 = ld_gfrag(wqb + 4096 + kk * 1024 + 512 + lo8);
      c0 = mfma16(xh[kk], f0, c0); c0 = mfma16(xl[kk], f0, c0); c0 = mfma16(xh[kk], g0, c0);
      c1 = mfma16(xh[kk], f1, c1); c1 = mfma16(xl[kk], f1, c1); c1 = mfma16(xh[kk], g1, c1);
    }
#pragma unroll
    for (int r = 0; r < 4; ++r) {      // C/D: row=quad*4+r, col=lane&15
      int row = (quad << 2) + r;
      unsigned short hi = f2bf(c0[r]), lo = f2bf(c0[r] - bf2f(hi));
      Qh[row * 36 + col] = hi; Ql[row * 36 + col] = lo;
      hi = f2bf(c1[r]); lo = f2bf(c1[r] - bf2f(hi));
      Qh[row * 36 + col + 16] = hi; Ql[row * 36 + col + 16] = lo;
    }

    // ======== K = x*WkT, 3-product split ========
    c0 = zero; c1 = zero;
#pragma unroll
    for (int kk = 0; kk < 4; ++kk) {
      bf16x8 f0 = ld_gfrag(wkb + kk * 1024 + lo8);
      bf16x8 f1 = ld_gfrag(wkb + kk * 1024 + 512 + lo8);
      bf16x8 g0 = ld_gfrag(wkb + 4096 + kk * 1024 + lo8);
      bf16x8 g1 = ld_gfrag(wkb + 4096 + kk * 1024 + 512 + lo8);
      c0 = mfma16(xh[kk], f0, c0); c0 = mfma16(xl[kk], f0, c0); c0 = mfma16(xh[kk], g0, c0);
      c1 = mfma16(xh[kk], f1, c1); c1 = mfma16(xl[kk], f1, c1); c1 = mfma16(xh[kk], g1, c1);
    }
#pragma unroll
    for (int r = 0; r < 4; ++r) {      // K global row t = sbase + ...
      int row = sbase + (quad << 2) + r;
      unsigned short hi = f2bf(c0[r]), lo = f2bf(c0[r] - bf2f(hi));
      Kh[row * 36 + col] = hi; Kl[row * 36 + col] = lo;
      hi = f2bf(c1[r]); lo = f2bf(c1[r] - bf2f(hi));
      Kh[row * 36 + col + 16] = hi; Kl[row * 36 + col + 16] = lo;
    }

    // ======== V = x*WvT, 2-product (x full precision, Wv bf16) ========
    c0 = zero; c1 = zero;
#pragma unroll
    for (int kk = 0; kk < 4; ++kk) {
      bf16x8 f0 = ld_gfrag(wvb + kk * 1024 + lo8);
      bf16x8 f1 = ld_gfrag(wvb + kk * 1024 + 512 + lo8);
      c0 = mfma16(xh[kk], f0, c0); c0 = mfma16(xl[kk], f0, c0);
      c1 = mfma16(xh[kk], f1, c1); c1 = mfma16(xl[kk], f1, c1);
    }
#pragma unroll
    for (int r = 0; r < 4; ++r) {      // V[t][d] -> Vt[d][t], hi only
      int t = sbase + (quad << 2) + r;
      Vth[col * 36 + t] = f2bf(c0[r]);
      Vth[(col + 16) * 36 + t] = f2bf(c1[r]);
    }
    __syncthreads();                   // K,V visible to sibling wave

    // ======== scores = Q*K^T (fp32-accurate, 3-product) ========
    f32x4 s0 = zero, s1 = zero;
    {
      bf16x8 qhf = ld_frag8(Qh + col * 36 + (quad << 3));
      bf16x8 qlf = ld_frag8(Ql + col * 36 + (quad << 3));
      bf16x8 k0 = ld_frag8(Kh + col * 36 + (quad << 3));
      bf16x8 k1 = ld_frag8(Kh + (col + 16) * 36 + (quad << 3));
      bf16x8 k0l = ld_frag8(Kl + col * 36 + (quad << 3));
      bf16x8 k1l = ld_frag8(Kl + (col + 16) * 36 + (quad << 3));
      s0 = mfma16(qhf, k0, s0); s0 = mfma16(qlf, k0, s0); s0 = mfma16(qhf, k0l, s0);
      s1 = mfma16(qhf, k1, s1); s1 = mfma16(qlf, k1, s1); s1 = mfma16(qhf, k1l, s1);
    }
    // ======== softmax over t in C-frag registers (16-lane shfl) ========
    float a0[4], a1[4];
#pragma unroll
    for (int r = 0; r < 4; ++r) {
      float v0 = s0[r], v1 = s1[r];
      float mx = fmaxf(v0, v1);
#pragma unroll
      for (int dx = 1; dx < 16; dx <<= 1) mx = fmaxf(mx, __shfl_xor(mx, dx));
      float e0 = __expf(v0 - mx), e1 = __expf(v1 - mx);
      float sm = e0 + e1;
#pragma unroll
      for (int dx = 1; dx < 16; dx <<= 1) sm += __shfl_xor(sm, dx);
      float inv = 1.0f / sm;
      a0[r] = e0 * inv; a1[r] = e1 * inv;
    }
    // A (bf16) into Qh -- same-wave round trip, Q-hi frags already consumed
#pragma unroll
    for (int r = 0; r < 4; ++r) {
      int row = (quad << 2) + r;       // local s row
      Qh[row * 36 + col] = f2bf(a0[r]);
      Qh[row * 36 + col + 16] = f2bf(a1[r]);
    }

    // ======== Hd = A*V ========
    f32x4 hv0 = zero, hv1 = zero;
    {
      bf16x8 af = ld_frag8(Qh + col * 36 + (quad << 3));
      bf16x8 v0h = ld_frag8(Vth + col * 36 + (quad << 3));
      bf16x8 v1h = ld_frag8(Vth + (col + 16) * 36 + (quad << 3));
      hv0 = mfma16(af, v0h, hv0);
      hv1 = mfma16(af, v1h, hv1);
    }
    // Hd hi/lo into Qh/Ql (same-wave)
#pragma unroll
    for (int r = 0; r < 4; ++r) {
      int row = (quad << 2) + r;
      unsigned short hi = f2bf(hv0[r]), lo = f2bf(hv0[r] - bf2f(hi));
      Qh[row * 36 + col] = hi; Ql[row * 36 + col] = lo;
      hi = f2bf(hv1[r]); lo = f2bf(hv1[r] - bf2f(hi));
      Qh[row * 36 + col + 16] = hi; Ql[row * 36 + col + 16] = lo;
    }

    // ======== out += Hd*Wo, 2-product (Hd full precision, Wo bf16) ========
    {
      bf16x8 dh = ld_frag8(Qh + col * 36 + (quad << 3));
      bf16x8 dl = ld_frag8(Ql + col * 36 + (quad << 3));
#pragma unroll
      for (int t8 = 0; t8 < 8; ++t8) {
        bf16x8 wh = ld_gfrag(wob + t8 * 512 + lo8);
        oacc[t8] = mfma16(dh, wh, oacc[t8]);
        oacc[t8] = mfma16(dl, wh, oacc[t8]);
      }
    }
  }  // head loop

  // ---- store out [16 rows][128 cols] fp32 ----
  float* og = out + batch * 4096;
#pragma unroll
  for (int t8 = 0; t8 < 8; ++t8) {
#pragma unroll
    for (int r = 0; r < 4; ++r) {
      og[(sbase + (quad << 2) + r) * 128 + (t8 << 4) + col] = oacc[t8][r];
    }
  }
}

extern "C" void kernel_launch(void* const* d_in, const int* in_sizes, int n_in,
                              void* d_out, int out_size, void* d_ws, size_t ws_size,
                              hipStream_t stream) {
  const float* x = (const float*)d_in[0];
  const float* wq = (const float*)d_in[1];
  const float* wk = (const float*)d_in[2];
  const float* wv = (const float*)d_in[3];
  const float* wo = (const float*)d_in[4];
  float* out = (float*)d_out;
  unsigned short* wsb = (unsigned short*)d_ws;  // needs 262144 B
  hipLaunchKernelGGL(prep_w, dim3(256), dim3(256), 0, stream, wq, wk, wv, wo, wsb);
  hipLaunchKernelGGL(attn_fused, dim3(8192), dim3(256), 0, stream, x, wsb, out);
}